// Round 3
// baseline (961.318 us; speedup 1.0000x reference)
//
#include <hip/hip_runtime.h>
#include <hip/hip_bf16.h>

typedef __attribute__((ext_vector_type(8))) short short8;   // 8 bf16 (4 VGPR)
typedef __attribute__((ext_vector_type(4))) float f32x4;
typedef __attribute__((ext_vector_type(2))) unsigned int u32x2;

constexpr int D_DIM = 512;
constexpr int S_DIM = 2048;
constexpr int BM    = 32;     // queries per block (32 -> 65.5KB LDS -> 2 blocks/CU)
constexpr int BN    = 512;    // keys per KV tile
constexpr int TILES = S_DIM / BN;

static __device__ __forceinline__ unsigned short f2bf(float f) {
  __hip_bfloat16 h = __float2bfloat16(f);
  return *reinterpret_cast<unsigned short*>(&h);
}

// ---- setup: L2-normalize keys -> bf16 Kn[S][D], one wave per row ----
__global__ void k_norm(const float* __restrict__ K, ushort* __restrict__ Kn) {
  const int row = blockIdx.x * 4 + (threadIdx.x >> 6);
  const int l   = threadIdx.x & 63;
  const float* src = K + (size_t)row * D_DIM + l * 8;
  float4 v0 = *(const float4*)(src);
  float4 v1 = *(const float4*)(src + 4);
  float ss = v0.x*v0.x + v0.y*v0.y + v0.z*v0.z + v0.w*v0.w
           + v1.x*v1.x + v1.y*v1.y + v1.z*v1.z + v1.w*v1.w;
  #pragma unroll
  for (int off = 1; off < 64; off <<= 1) ss += __shfl_xor(ss, off, 64);
  const float sc = 1.0f / fmaxf(sqrtf(ss), 1e-12f);
  float f[8] = {v0.x,v0.y,v0.z,v0.w,v1.x,v1.y,v1.z,v1.w};
  unsigned uu[4];
  #pragma unroll
  for (int i = 0; i < 4; ++i)
    uu[i] = (unsigned)f2bf(f[2*i]*sc) | ((unsigned)f2bf(f[2*i+1]*sc) << 16);
  *(uint4*)(Kn + (size_t)row * D_DIM + l*8) = make_uint4(uu[0],uu[1],uu[2],uu[3]);
}

// ---- setup: transpose V[S][D] f32 -> Vt[D][S] bf16 ----
__global__ void k_transpose_v(const float* __restrict__ V, ushort* __restrict__ Vt) {
  __shared__ float tile[64][65];
  const int s0 = blockIdx.x * 64;
  const int d0 = blockIdx.y * 64;
  const int tj = threadIdx.x & 63;
  const int ti = threadIdx.x >> 6;
  #pragma unroll
  for (int k = 0; k < 16; ++k) {
    int s = ti + 4*k;
    tile[s][tj] = V[(size_t)(s0+s) * D_DIM + d0 + tj];
  }
  __syncthreads();
  #pragma unroll
  for (int k = 0; k < 16; ++k) {
    int d = ti + 4*k;
    Vt[(size_t)(d0+d) * S_DIM + s0 + tj] = f2bf(tile[tj][d]);
  }
}

// ---- fused attention: per block 32 queries, loop 4 KV tiles of 512 keys ----
// Scores are cosines in [-1,1] -> no online max: p = exp(s), divide by rowsum.
// QK^T computed transposed (S^T = Kn * Q^T) so P frags pack row-major into LDS.
// LDS swizzle: byte = row*1024 + (linear_col_bytes ^ ((row&7)<<4)); reads and
// writes both apply pure XOR to the FULL linear column offset (no adds across
// bits 4..6 -> no carries into the swizzle field).
__global__ __launch_bounds__(512, 4) void attn_main(
    const float* __restrict__ Q, const ushort* __restrict__ Kn,
    const ushort* __restrict__ Vt, float* __restrict__ out)
{
  __shared__ ushort q_s[BM * D_DIM];   // 32KB, swizzled bf16
  __shared__ ushort p_s[BM * BN];      // 32KB, swizzled bf16
  __shared__ float  rs_lds[8 * BM];    // per-wave rowsum partials
  __shared__ float  rs_tot[BM];

  char* qb = (char*)q_s;
  char* pb = (char*)p_s;

  const int tid = threadIdx.x;
  const int w   = tid >> 6;
  const int l   = tid & 63;
  const int lhi = l >> 4;
  const int llo = l & 15;
  const size_t q0 = (size_t)blockIdx.x * BM;

  // ---- stage Q: normalize rows, bf16 into swizzled q_s (16 threads/row) ----
  {
    const int row = tid >> 4;            // 0..31
    const int c0  = (tid & 15) * 32;     // float col
    const unsigned swzr = (unsigned)((row & 7) << 4);
    const float4* src = (const float4*)(Q + (q0 + row) * D_DIM + c0);
    float v[32];
    float ss = 0.f;
    #pragma unroll
    for (int i = 0; i < 8; ++i) {
      float4 t4 = src[i];
      v[4*i+0] = t4.x; v[4*i+1] = t4.y; v[4*i+2] = t4.z; v[4*i+3] = t4.w;
      ss += t4.x*t4.x + t4.y*t4.y + t4.z*t4.z + t4.w*t4.w;
    }
    ss += __shfl_xor(ss, 1, 64);
    ss += __shfl_xor(ss, 2, 64);
    ss += __shfl_xor(ss, 4, 64);
    ss += __shfl_xor(ss, 8, 64);
    const float sc = 1.0f / fmaxf(sqrtf(ss), 1e-12f);
    #pragma unroll
    for (int j = 0; j < 4; ++j) {
      unsigned uu[4];
      #pragma unroll
      for (int i = 0; i < 4; ++i)
        uu[i] = (unsigned)f2bf(v[8*j+2*i]*sc) | ((unsigned)f2bf(v[8*j+2*i+1]*sc) << 16);
      unsigned byte = (unsigned)(row*1024) + (((unsigned)(c0*2 + j*16)) ^ swzr);
      *(uint4*)(qb + byte) = make_uint4(uu[0],uu[1],uu[2],uu[3]);
    }
  }
  __syncthreads();

  f32x4 o[2][4] = {};                  // [qfrag][dfrag], row=query col=dim
  float rs_acc[2] = {0.f, 0.f};

  const unsigned swz = (unsigned)((l & 7) << 4);  // row&7 == llo&7 == l&7 for row=qf*16+llo
  unsigned rowb[2];                    // un-swizzled LDS row base per query-frag
  #pragma unroll
  for (int qf = 0; qf < 2; ++qf)
    rowb[qf] = (unsigned)((qf*16 + llo) * 1024);

  for (int t = 0; t < TILES; ++t) {
    const int s0 = t * BN;

    // ---- QK^T (transposed): sacc[kf][qf], row=key col=query ----
    const short8* kp[4];
    #pragma unroll
    for (int kf = 0; kf < 4; ++kf)
      kp[kf] = (const short8*)(Kn + (size_t)(s0 + w*64 + kf*16 + llo) * D_DIM + lhi*8);

    f32x4 sacc[4][2] = {};
    #pragma unroll
    for (int ks = 0; ks < 16; ++ks) {  // d0 = ks*32
      const unsigned off = ((unsigned)(ks*64 + lhi*16)) ^ swz;  // pure XOR, no carry
      short8 a[4], b[2];
      #pragma unroll
      for (int kf = 0; kf < 4; ++kf) a[kf] = kp[kf][ks*4];
      #pragma unroll
      for (int qf = 0; qf < 2; ++qf)
        b[qf] = *(const short8*)(qb + (rowb[qf] + off));
      #pragma unroll
      for (int kf = 0; kf < 4; ++kf)
        #pragma unroll
        for (int qf = 0; qf < 2; ++qf)
          sacc[kf][qf] = __builtin_amdgcn_mfma_f32_16x16x32_bf16(a[kf], b[qf], sacc[kf][qf], 0, 0, 0);
    }

    // ---- exp + rowsum partials + pack to bf16 (registers) ----
    u32x2 pk[4][2];
    #pragma unroll
    for (int kf = 0; kf < 4; ++kf) {
      #pragma unroll
      for (int qf = 0; qf < 2; ++qf) {
        float p0 = __expf(sacc[kf][qf][0]);
        float p1 = __expf(sacc[kf][qf][1]);
        float p2 = __expf(sacc[kf][qf][2]);
        float p3 = __expf(sacc[kf][qf][3]);
        rs_acc[qf] += (p0 + p1) + (p2 + p3);
        u32x2 pv;
        pv[0] = (unsigned)f2bf(p0) | ((unsigned)f2bf(p1) << 16);
        pv[1] = (unsigned)f2bf(p2) | ((unsigned)f2bf(p3) << 16);
        pk[kf][qf] = pv;
      }
    }

    __syncthreads();   // previous tile's PV reads of p_s are done
    #pragma unroll
    for (int kf = 0; kf < 4; ++kf) {
      #pragma unroll
      for (int qf = 0; qf < 2; ++qf) {
        // row = qf*16+llo; linear col bytes = w*128 + kf*32 + lhi*8
        unsigned lin = (unsigned)(w*128 + kf*32 + lhi*8);
        unsigned byte = rowb[qf] + (lin ^ swz);
        *(u32x2*)(pb + byte) = pk[kf][qf];
      }
    }
    __syncthreads();   // p_s ready

    // ---- PV: o += P(32q x 512k) * V(512k x 64d-per-wave) ----
    const short8* vp[4];
    #pragma unroll
    for (int df = 0; df < 4; ++df)
      vp[df] = (const short8*)(Vt + (size_t)(w*64 + df*16 + llo) * S_DIM + s0 + lhi*8);
    #pragma unroll
    for (int ks = 0; ks < 16; ++ks) {  // key chunk = ks*32
      const unsigned off = ((unsigned)(ks*64 + lhi*16)) ^ swz;
      short8 a[2], b[4];
      #pragma unroll
      for (int qf = 0; qf < 2; ++qf)
        a[qf] = *(const short8*)(pb + (rowb[qf] + off));
      #pragma unroll
      for (int df = 0; df < 4; ++df) b[df] = vp[df][ks*4];
      #pragma unroll
      for (int qf = 0; qf < 2; ++qf)
        #pragma unroll
        for (int df = 0; df < 4; ++df)
          o[qf][df] = __builtin_amdgcn_mfma_f32_16x16x32_bf16(a[qf], b[df], o[qf][df], 0, 0, 0);
    }
  }

  // ---- rowsum: reduce lane partials across lhi groups, then across waves ----
  #pragma unroll
  for (int qf = 0; qf < 2; ++qf) {
    float v = rs_acc[qf];
    v += __shfl_xor(v, 16, 64);
    v += __shfl_xor(v, 32, 64);
    if (l < 16) rs_lds[w*32 + qf*16 + llo] = v;
  }
  __syncthreads();
  if (tid < 32) {
    float tot = 0.f;
    #pragma unroll
    for (int ww = 0; ww < 8; ++ww) tot += rs_lds[ww*32 + tid];
    rs_tot[tid] = tot;
  }
  __syncthreads();

  // ---- normalize + store ----
  #pragma unroll
  for (int qf = 0; qf < 2; ++qf) {
    #pragma unroll
    for (int r = 0; r < 4; ++r) {
      const int query = qf*16 + lhi*4 + r;
      const float inv = 1.0f / rs_tot[query];
      #pragma unroll
      for (int df = 0; df < 4; ++df) {
        const int dim = w*64 + df*16 + llo;
        out[(q0 + query) * D_DIM + dim] = o[qf][df][r] * inv;
      }
    }
  }
}

extern "C" void kernel_launch(void* const* d_in, const int* in_sizes, int n_in,
                              void* d_out, int out_size, void* d_ws, size_t ws_size,
                              hipStream_t stream) {
  const float* Q = (const float*)d_in[0];
  const float* K = (const float*)d_in[1];
  const float* V = (const float*)d_in[2];
  float* out = (float*)d_out;
  const int N = in_sizes[0] / D_DIM;          // 65536

  ushort* Kn = (ushort*)d_ws;                 // [S][D] bf16, 2MB
  ushort* Vt = Kn + (size_t)S_DIM * D_DIM;    // [D][S] bf16, 2MB

  k_norm<<<S_DIM/4, 256, 0, stream>>>(K, Kn);
  k_transpose_v<<<dim3(S_DIM/64, D_DIM/64), 256, 0, stream>>>(V, Vt);
  attn_main<<<N/BM, 512, 0, stream>>>(Q, Kn, Vt, out);
}

// Round 4
// 558.841 us; speedup vs baseline: 1.7202x; 1.7202x over previous
//
#include <hip/hip_runtime.h>
#include <hip/hip_bf16.h>

typedef __attribute__((ext_vector_type(8))) short short8;   // 8 bf16 (4 VGPR)
typedef __attribute__((ext_vector_type(4))) float f32x4;
typedef __attribute__((ext_vector_type(2))) unsigned int u32x2;

constexpr int D_DIM = 512;
constexpr int S_DIM = 2048;
constexpr int BM    = 64;     // queries per block
constexpr int BN    = 512;    // keys per KV tile
constexpr int TILES = S_DIM / BN;
constexpr int NW    = 16;     // waves per block (1024 threads)

static __device__ __forceinline__ unsigned short f2bf(float f) {
  __hip_bfloat16 h = __float2bfloat16(f);
  return *reinterpret_cast<unsigned short*>(&h);
}

// ---- setup: L2-normalize keys -> bf16 Kn[S][D], one wave per row ----
__global__ void k_norm(const float* __restrict__ K, ushort* __restrict__ Kn) {
  const int row = blockIdx.x * 4 + (threadIdx.x >> 6);
  const int l   = threadIdx.x & 63;
  const float* src = K + (size_t)row * D_DIM + l * 8;
  float4 v0 = *(const float4*)(src);
  float4 v1 = *(const float4*)(src + 4);
  float ss = v0.x*v0.x + v0.y*v0.y + v0.z*v0.z + v0.w*v0.w
           + v1.x*v1.x + v1.y*v1.y + v1.z*v1.z + v1.w*v1.w;
  #pragma unroll
  for (int off = 1; off < 64; off <<= 1) ss += __shfl_xor(ss, off, 64);
  const float sc = 1.0f / fmaxf(sqrtf(ss), 1e-12f);
  float f[8] = {v0.x,v0.y,v0.z,v0.w,v1.x,v1.y,v1.z,v1.w};
  unsigned uu[4];
  #pragma unroll
  for (int i = 0; i < 4; ++i)
    uu[i] = (unsigned)f2bf(f[2*i]*sc) | ((unsigned)f2bf(f[2*i+1]*sc) << 16);
  *(uint4*)(Kn + (size_t)row * D_DIM + l*8) = make_uint4(uu[0],uu[1],uu[2],uu[3]);
}

// ---- setup: transpose V[S][D] f32 -> Vt[D][S] bf16 ----
__global__ void k_transpose_v(const float* __restrict__ V, ushort* __restrict__ Vt) {
  __shared__ float tile[64][65];
  const int s0 = blockIdx.x * 64;
  const int d0 = blockIdx.y * 64;
  const int tj = threadIdx.x & 63;
  const int ti = threadIdx.x >> 6;
  #pragma unroll
  for (int k = 0; k < 16; ++k) {
    int s = ti + 4*k;
    tile[s][tj] = V[(size_t)(s0+s) * D_DIM + d0 + tj];
  }
  __syncthreads();
  #pragma unroll
  for (int k = 0; k < 16; ++k) {
    int d = ti + 4*k;
    Vt[(size_t)(d0+d) * S_DIM + s0 + tj] = f2bf(tile[tj][d]);
  }
}

// ---- fused attention: 1024 threads (16 waves), 64 queries/block ----
// Scores are cosines in [-1,1] -> no online max: p = exp(s), divide by rowsum.
// QK^T computed transposed (S^T = Kn * Q^T): wave owns 32 keys; P frags pack
// row-major (swizzled) into LDS; PV: wave owns 32 dims over all 512 keys.
// LDS swizzle: byte = row*1024 + (linear_col_bytes ^ ((row&7)<<4)); the XOR is
// always applied to the FULL linear column offset (carry-free).
__global__ __launch_bounds__(1024, 4) void attn_main(
    const float* __restrict__ Q, const ushort* __restrict__ Kn,
    const ushort* __restrict__ Vt, float* __restrict__ out)
{
  __shared__ ushort q_s[BM * D_DIM];   // 64KB, swizzled bf16
  __shared__ ushort p_s[BM * BN];      // 64KB, swizzled bf16
  __shared__ float  rs_lds[NW * BM];   // per-wave rowsum partials (4KB)
  __shared__ float  rs_tot[BM];

  char* qb = (char*)q_s;
  char* pb = (char*)p_s;

  const int tid = threadIdx.x;
  const int w   = tid >> 6;            // 0..15
  const int l   = tid & 63;
  const int lhi = l >> 4;
  const int llo = l & 15;
  const size_t q0 = (size_t)blockIdx.x * BM;

  // ---- stage Q: normalize rows, bf16 into swizzled q_s (16 threads/row) ----
  {
    const int row = tid >> 4;            // 0..63
    const int c0  = (tid & 15) * 32;     // float col
    const unsigned swzr = (unsigned)((row & 7) << 4);
    const float4* src = (const float4*)(Q + (q0 + row) * D_DIM + c0);
    float v[32];
    float ss = 0.f;
    #pragma unroll
    for (int i = 0; i < 8; ++i) {
      float4 t4 = src[i];
      v[4*i+0] = t4.x; v[4*i+1] = t4.y; v[4*i+2] = t4.z; v[4*i+3] = t4.w;
      ss += t4.x*t4.x + t4.y*t4.y + t4.z*t4.z + t4.w*t4.w;
    }
    ss += __shfl_xor(ss, 1, 64);
    ss += __shfl_xor(ss, 2, 64);
    ss += __shfl_xor(ss, 4, 64);
    ss += __shfl_xor(ss, 8, 64);
    const float sc = 1.0f / fmaxf(sqrtf(ss), 1e-12f);
    #pragma unroll
    for (int j = 0; j < 4; ++j) {
      unsigned uu[4];
      #pragma unroll
      for (int i = 0; i < 4; ++i)
        uu[i] = (unsigned)f2bf(v[8*j+2*i]*sc) | ((unsigned)f2bf(v[8*j+2*i+1]*sc) << 16);
      unsigned byte = (unsigned)(row*1024) + (((unsigned)(c0*2 + j*16)) ^ swzr);
      *(uint4*)(qb + byte) = make_uint4(uu[0],uu[1],uu[2],uu[3]);
    }
  }
  __syncthreads();

  f32x4 o[4][2] = {};                  // [qfrag][dfrag], row=query col=dim
  float rs_acc[4] = {0.f, 0.f, 0.f, 0.f};

  const unsigned swz = (unsigned)((l & 7) << 4);  // row&7 == llo&7 for row=qf*16+llo
  unsigned rowb[4];                    // un-swizzled LDS row base per query-frag
  #pragma unroll
  for (int qf = 0; qf < 4; ++qf)
    rowb[qf] = (unsigned)((qf*16 + llo) * 1024);

  for (int t = 0; t < TILES; ++t) {
    const int s0 = t * BN;

    // ---- QK^T (transposed): sacc[kf][qf], row=key col=query; 32 keys/wave ----
    const short8* kp[2];
    #pragma unroll
    for (int kf = 0; kf < 2; ++kf)
      kp[kf] = (const short8*)(Kn + (size_t)(s0 + w*32 + kf*16 + llo) * D_DIM + lhi*8);

    f32x4 sacc[2][4] = {};
    __builtin_amdgcn_s_setprio(1);
    #pragma unroll
    for (int ks = 0; ks < 16; ++ks) {  // d0 = ks*32
      const unsigned off = ((unsigned)(ks*64 + lhi*16)) ^ swz;  // pure XOR
      short8 a[2], b[4];
      #pragma unroll
      for (int kf = 0; kf < 2; ++kf) a[kf] = kp[kf][ks*4];
      #pragma unroll
      for (int qf = 0; qf < 4; ++qf)
        b[qf] = *(const short8*)(qb + (rowb[qf] + off));
      #pragma unroll
      for (int kf = 0; kf < 2; ++kf)
        #pragma unroll
        for (int qf = 0; qf < 4; ++qf)
          sacc[kf][qf] = __builtin_amdgcn_mfma_f32_16x16x32_bf16(a[kf], b[qf], sacc[kf][qf], 0, 0, 0);
    }
    __builtin_amdgcn_s_setprio(0);

    // ---- exp + rowsum partials + pack to bf16 (registers) ----
    u32x2 pk[2][4];
    #pragma unroll
    for (int kf = 0; kf < 2; ++kf) {
      #pragma unroll
      for (int qf = 0; qf < 4; ++qf) {
        float p0 = __expf(sacc[kf][qf][0]);
        float p1 = __expf(sacc[kf][qf][1]);
        float p2 = __expf(sacc[kf][qf][2]);
        float p3 = __expf(sacc[kf][qf][3]);
        rs_acc[qf] += (p0 + p1) + (p2 + p3);
        u32x2 pv;
        pv[0] = (unsigned)f2bf(p0) | ((unsigned)f2bf(p1) << 16);
        pv[1] = (unsigned)f2bf(p2) | ((unsigned)f2bf(p3) << 16);
        pk[kf][qf] = pv;
      }
    }

    __syncthreads();   // previous tile's PV reads of p_s are done
    #pragma unroll
    for (int kf = 0; kf < 2; ++kf) {
      #pragma unroll
      for (int qf = 0; qf < 4; ++qf) {
        // row = qf*16+llo; linear col bytes = w*64 + kf*32 + lhi*8
        unsigned lin = (unsigned)(w*64 + kf*32 + lhi*8);
        unsigned byte = rowb[qf] + (lin ^ swz);   // XOR over full lin (carry-free)
        *(u32x2*)(pb + byte) = pk[kf][qf];
      }
    }
    __syncthreads();   // p_s ready

    // ---- PV: o += P(64q x 512k) * V(512k x 32d-per-wave) ----
    const short8* vp[2];
    #pragma unroll
    for (int df = 0; df < 2; ++df)
      vp[df] = (const short8*)(Vt + (size_t)(w*32 + df*16 + llo) * S_DIM + s0 + lhi*8);
    __builtin_amdgcn_s_setprio(1);
    #pragma unroll
    for (int ks = 0; ks < 16; ++ks) {  // key chunk = ks*32
      const unsigned off = ((unsigned)(ks*64 + lhi*16)) ^ swz;
      short8 a[4], b[2];
      #pragma unroll
      for (int qf = 0; qf < 4; ++qf)
        a[qf] = *(const short8*)(pb + (rowb[qf] + off));
      #pragma unroll
      for (int df = 0; df < 2; ++df) b[df] = vp[df][ks*4];
      #pragma unroll
      for (int qf = 0; qf < 4; ++qf)
        #pragma unroll
        for (int df = 0; df < 2; ++df)
          o[qf][df] = __builtin_amdgcn_mfma_f32_16x16x32_bf16(a[qf], b[df], o[qf][df], 0, 0, 0);
    }
    __builtin_amdgcn_s_setprio(0);
  }

  // ---- rowsum: reduce lane partials across lhi groups, then across waves ----
  #pragma unroll
  for (int qf = 0; qf < 4; ++qf) {
    float v = rs_acc[qf];
    v += __shfl_xor(v, 16, 64);
    v += __shfl_xor(v, 32, 64);
    if (l < 16) rs_lds[w*BM + qf*16 + llo] = v;
  }
  __syncthreads();
  if (tid < BM) {
    float tot = 0.f;
    #pragma unroll
    for (int ww = 0; ww < NW; ++ww) tot += rs_lds[ww*BM + tid];
    rs_tot[tid] = tot;
  }
  __syncthreads();

  // ---- normalize + store ----
  #pragma unroll
  for (int qf = 0; qf < 4; ++qf) {
    #pragma unroll
    for (int r = 0; r < 4; ++r) {
      const int query = qf*16 + lhi*4 + r;
      const float inv = 1.0f / rs_tot[query];
      #pragma unroll
      for (int df = 0; df < 2; ++df) {
        const int dim = w*32 + df*16 + llo;
        out[(q0 + query) * D_DIM + dim] = o[qf][df][r] * inv;
      }
    }
  }
}

extern "C" void kernel_launch(void* const* d_in, const int* in_sizes, int n_in,
                              void* d_out, int out_size, void* d_ws, size_t ws_size,
                              hipStream_t stream) {
  const float* Q = (const float*)d_in[0];
  const float* K = (const float*)d_in[1];
  const float* V = (const float*)d_in[2];
  float* out = (float*)d_out;
  const int N = in_sizes[0] / D_DIM;          // 65536

  ushort* Kn = (ushort*)d_ws;                 // [S][D] bf16, 2MB
  ushort* Vt = Kn + (size_t)S_DIM * D_DIM;    // [D][S] bf16, 2MB

  k_norm<<<S_DIM/4, 256, 0, stream>>>(K, Kn);
  k_transpose_v<<<dim3(S_DIM/64, D_DIM/64), 256, 0, stream>>>(V, Vt);
  attn_main<<<N/BM, 1024, 0, stream>>>(Q, Kn, Vt, out);
}

// Round 5
// 515.787 us; speedup vs baseline: 1.8638x; 1.0835x over previous
//
#include <hip/hip_runtime.h>
#include <hip/hip_bf16.h>

typedef __attribute__((ext_vector_type(8))) short short8;   // 8 bf16 (4 VGPR)
typedef __attribute__((ext_vector_type(4))) float f32x4;
typedef __attribute__((ext_vector_type(2))) unsigned int u32x2;

constexpr int D_DIM = 512;
constexpr int S_DIM = 2048;
constexpr int BM    = 64;     // queries per block
constexpr int BH    = 256;    // keys per half-tile (ping-pong granularity)
constexpr int NH    = S_DIM / BH;   // 8 halves
constexpr int NW    = 16;     // waves per block (1024 threads)
constexpr int PBUF  = BM * BH * 2;  // bytes per P buffer (32KB)

static __device__ __forceinline__ unsigned short f2bf(float f) {
  __hip_bfloat16 h = __float2bfloat16(f);
  return *reinterpret_cast<unsigned short*>(&h);
}

// ---- setup: L2-normalize keys -> bf16 Kn[S][D], one wave per row ----
__global__ void k_norm(const float* __restrict__ K, ushort* __restrict__ Kn) {
  const int row = blockIdx.x * 4 + (threadIdx.x >> 6);
  const int l   = threadIdx.x & 63;
  const float* src = K + (size_t)row * D_DIM + l * 8;
  float4 v0 = *(const float4*)(src);
  float4 v1 = *(const float4*)(src + 4);
  float ss = v0.x*v0.x + v0.y*v0.y + v0.z*v0.z + v0.w*v0.w
           + v1.x*v1.x + v1.y*v1.y + v1.z*v1.z + v1.w*v1.w;
  #pragma unroll
  for (int off = 1; off < 64; off <<= 1) ss += __shfl_xor(ss, off, 64);
  const float sc = 1.0f / fmaxf(sqrtf(ss), 1e-12f);
  float f[8] = {v0.x,v0.y,v0.z,v0.w,v1.x,v1.y,v1.z,v1.w};
  unsigned uu[4];
  #pragma unroll
  for (int i = 0; i < 4; ++i)
    uu[i] = (unsigned)f2bf(f[2*i]*sc) | ((unsigned)f2bf(f[2*i+1]*sc) << 16);
  *(uint4*)(Kn + (size_t)row * D_DIM + l*8) = make_uint4(uu[0],uu[1],uu[2],uu[3]);
}

// ---- setup: transpose V[S][D] f32 -> Vt[D][S] bf16 ----
__global__ void k_transpose_v(const float* __restrict__ V, ushort* __restrict__ Vt) {
  __shared__ float tile[64][65];
  const int s0 = blockIdx.x * 64;
  const int d0 = blockIdx.y * 64;
  const int tj = threadIdx.x & 63;
  const int ti = threadIdx.x >> 6;
  #pragma unroll
  for (int k = 0; k < 16; ++k) {
    int s = ti + 4*k;
    tile[s][tj] = V[(size_t)(s0+s) * D_DIM + d0 + tj];
  }
  __syncthreads();
  #pragma unroll
  for (int k = 0; k < 16; ++k) {
    int d = ti + 4*k;
    Vt[(size_t)(d0+d) * S_DIM + s0 + tj] = f2bf(tile[tj][d]);
  }
}

// ---- fused attention: 1024 threads (16 waves), 64 queries/block ----
// Scores are cosines in [-1,1] -> no online max: p = exp(s), divide by rowsum.
// Ping-pong over 8 half-tiles of 256 keys with double-buffered P in LDS:
// one region = { QK^T(h+1) ; exp/pack ; PV(h) ; write p_s[(h+1)&1] } ; barrier.
// QK^T transposed (S^T = Kn * Q^T): wave owns 16 keys; PV: wave owns 32 dims.
// LDS swizzle: byte = row*stride + (linear_col_bytes ^ ((row&7)<<4)); XOR is
// always applied to the FULL linear column offset (carry-free).
__global__ __launch_bounds__(1024, 4) void attn_main(
    const float* __restrict__ Q, const ushort* __restrict__ Kn,
    const ushort* __restrict__ Vt, float* __restrict__ out)
{
  __shared__ ushort q_s[BM * D_DIM];     // 64KB, swizzled bf16 (row stride 1024B)
  __shared__ ushort p_s[2 * BM * BH];    // 2 x 32KB, swizzled bf16 (row stride 512B)
  __shared__ float  rs_lds[NW * BM];     // per-wave rowsum partials (4KB)
  __shared__ float  rs_tot[BM];

  char* qb = (char*)q_s;
  char* pb = (char*)p_s;

  const int tid = threadIdx.x;
  const int w   = tid >> 6;            // 0..15
  const int l   = tid & 63;
  const int lhi = l >> 4;
  const int llo = l & 15;
  const size_t q0 = (size_t)blockIdx.x * BM;

  // ---- stage Q: normalize rows, bf16 into swizzled q_s (16 threads/row) ----
  {
    const int row = tid >> 4;            // 0..63
    const int c0  = (tid & 15) * 32;     // float col
    const unsigned swzr = (unsigned)((row & 7) << 4);
    const float4* src = (const float4*)(Q + (q0 + row) * D_DIM + c0);
    float v[32];
    float ss = 0.f;
    #pragma unroll
    for (int i = 0; i < 8; ++i) {
      float4 t4 = src[i];
      v[4*i+0] = t4.x; v[4*i+1] = t4.y; v[4*i+2] = t4.z; v[4*i+3] = t4.w;
      ss += t4.x*t4.x + t4.y*t4.y + t4.z*t4.z + t4.w*t4.w;
    }
    ss += __shfl_xor(ss, 1, 64);
    ss += __shfl_xor(ss, 2, 64);
    ss += __shfl_xor(ss, 4, 64);
    ss += __shfl_xor(ss, 8, 64);
    const float sc = 1.0f / fmaxf(sqrtf(ss), 1e-12f);
    #pragma unroll
    for (int j = 0; j < 4; ++j) {
      unsigned uu[4];
      #pragma unroll
      for (int i = 0; i < 4; ++i)
        uu[i] = (unsigned)f2bf(v[8*j+2*i]*sc) | ((unsigned)f2bf(v[8*j+2*i+1]*sc) << 16);
      unsigned byte = (unsigned)(row*1024) + (((unsigned)(c0*2 + j*16)) ^ swzr);
      *(uint4*)(qb + byte) = make_uint4(uu[0],uu[1],uu[2],uu[3]);
    }
  }
  __syncthreads();

  f32x4 o[4][2] = {};                  // [qfrag][dfrag], row=query col=dim
  float rs_acc[4] = {0.f, 0.f, 0.f, 0.f};

  const unsigned swz = (unsigned)((l & 7) << 4);  // row&7 == llo&7 for row=qf*16+llo
  unsigned rowbQ[4];                   // q_s row base (stride 1024)
  unsigned rowbP[4];                   // p_s row base (stride 512)
  #pragma unroll
  for (int qf = 0; qf < 4; ++qf) {
    rowbQ[qf] = (unsigned)((qf*16 + llo) * 1024);
    rowbP[qf] = (unsigned)((qf*16 + llo) * 512);
  }

  // QK^T for half h -> sacc[qf] (wave owns keys h*BH + w*16 + llo .. +15)
  auto do_qkt = [&](int h, f32x4 (&sacc)[4]) {
    const short8* kp = (const short8*)(Kn + (size_t)(h*BH + w*16 + llo) * D_DIM + lhi*8);
    __builtin_amdgcn_s_setprio(1);
    #pragma unroll
    for (int ks = 0; ks < 16; ++ks) {  // dims ks*32 .. +31
      const unsigned off = ((unsigned)(ks*64 + lhi*16)) ^ swz;
      short8 a = kp[ks*4];
      short8 b[4];
      #pragma unroll
      for (int qf = 0; qf < 4; ++qf)
        b[qf] = *(const short8*)(qb + (rowbQ[qf] + off));
      #pragma unroll
      for (int qf = 0; qf < 4; ++qf)
        sacc[qf] = __builtin_amdgcn_mfma_f32_16x16x32_bf16(a, b[qf], sacc[qf], 0, 0, 0);
    }
    __builtin_amdgcn_s_setprio(0);
  };

  // exp + rowsum partials + pack to bf16
  auto do_exp = [&](f32x4 (&sacc)[4], u32x2 (&pk)[4]) {
    #pragma unroll
    for (int qf = 0; qf < 4; ++qf) {
      float p0 = __expf(sacc[qf][0]);
      float p1 = __expf(sacc[qf][1]);
      float p2 = __expf(sacc[qf][2]);
      float p3 = __expf(sacc[qf][3]);
      rs_acc[qf] += (p0 + p1) + (p2 + p3);
      pk[qf][0] = (unsigned)f2bf(p0) | ((unsigned)f2bf(p1) << 16);
      pk[qf][1] = (unsigned)f2bf(p2) | ((unsigned)f2bf(p3) << 16);
    }
  };

  // write packed P for half h into buffer buf (key-local k = w*16 + lhi*4 + r)
  auto do_pwrite = [&](u32x2 (&pk)[4], char* buf) {
    #pragma unroll
    for (int qf = 0; qf < 4; ++qf) {
      unsigned lin = (unsigned)(w*32 + lhi*8);
      *(u32x2*)(buf + rowbP[qf] + (lin ^ swz)) = pk[qf];
    }
  };

  // PV for half h from buffer buf: o += P(64q x 256k) * V(256k x 32d-per-wave)
  auto do_pv = [&](int h, const char* buf) {
    const short8* vp[2];
    #pragma unroll
    for (int df = 0; df < 2; ++df)
      vp[df] = (const short8*)(Vt + (size_t)(w*32 + df*16 + llo) * S_DIM + h*BH + lhi*8);
    __builtin_amdgcn_s_setprio(1);
    #pragma unroll
    for (int ks = 0; ks < 8; ++ks) {   // keys ks*32 .. +31 (local)
      const unsigned off = ((unsigned)(ks*64 + lhi*16)) ^ swz;
      short8 a[4], b[2];
      #pragma unroll
      for (int qf = 0; qf < 4; ++qf)
        a[qf] = *(const short8*)(buf + (rowbP[qf] + off));
      #pragma unroll
      for (int df = 0; df < 2; ++df) b[df] = vp[df][ks*4];
      #pragma unroll
      for (int qf = 0; qf < 4; ++qf)
        #pragma unroll
        for (int df = 0; df < 2; ++df)
          o[qf][df] = __builtin_amdgcn_mfma_f32_16x16x32_bf16(a[qf], b[df], o[qf][df], 0, 0, 0);
    }
    __builtin_amdgcn_s_setprio(0);
  };

  // ---- prologue: compute P(0) into buffer 0 ----
  {
    f32x4 sacc[4] = {};
    do_qkt(0, sacc);
    u32x2 pk[4];
    do_exp(sacc, pk);
    do_pwrite(pk, pb + 0);
  }
  __syncthreads();

  // ---- main ping-pong: one barrier per half-tile ----
  for (int i = 0; i < NH - 1; ++i) {
    f32x4 sacc[4] = {};
    do_qkt(i + 1, sacc);               // next half's scores (K from L2, Q from LDS)
    u32x2 pk[4];
    do_exp(sacc, pk);
    do_pv(i, pb + (i & 1) * PBUF);     // current half's PV (reads buffer i&1)
    do_pwrite(pk, pb + ((i + 1) & 1) * PBUF);  // write other buffer
    __syncthreads();
  }
  do_pv(NH - 1, pb + ((NH - 1) & 1) * PBUF);

  // ---- rowsum: reduce lane partials across lhi groups, then across waves ----
  #pragma unroll
  for (int qf = 0; qf < 4; ++qf) {
    float v = rs_acc[qf];
    v += __shfl_xor(v, 16, 64);
    v += __shfl_xor(v, 32, 64);
    if (l < 16) rs_lds[w*BM + qf*16 + llo] = v;
  }
  __syncthreads();
  if (tid < BM) {
    float tot = 0.f;
    #pragma unroll
    for (int ww = 0; ww < NW; ++ww) tot += rs_lds[ww*BM + tid];
    rs_tot[tid] = tot;
  }
  __syncthreads();

  // ---- normalize + store ----
  #pragma unroll
  for (int qf = 0; qf < 4; ++qf) {
    #pragma unroll
    for (int r = 0; r < 4; ++r) {
      const int query = qf*16 + lhi*4 + r;
      const float inv = 1.0f / rs_tot[query];
      #pragma unroll
      for (int df = 0; df < 2; ++df) {
        const int dim = w*32 + df*16 + llo;
        out[(q0 + query) * D_DIM + dim] = o[qf][df][r] * inv;
      }
    }
  }
}

extern "C" void kernel_launch(void* const* d_in, const int* in_sizes, int n_in,
                              void* d_out, int out_size, void* d_ws, size_t ws_size,
                              hipStream_t stream) {
  const float* Q = (const float*)d_in[0];
  const float* K = (const float*)d_in[1];
  const float* V = (const float*)d_in[2];
  float* out = (float*)d_out;
  const int N = in_sizes[0] / D_DIM;          // 65536

  ushort* Kn = (ushort*)d_ws;                 // [S][D] bf16, 2MB
  ushort* Vt = Kn + (size_t)S_DIM * D_DIM;    // [D][S] bf16, 2MB

  k_norm<<<S_DIM/4, 256, 0, stream>>>(K, Kn);
  k_transpose_v<<<dim3(S_DIM/64, D_DIM/64), 256, 0, stream>>>(V, Vt);
  attn_main<<<N/BM, 1024, 0, stream>>>(Q, Kn, Vt, out);
}